// Round 13
// baseline (365.327 us; speedup 1.0000x reference)
//
#include <hip/hip_runtime.h>
#include <hip/hip_bf16.h>
#include <math.h>

#define S 256
#define N 512
#define CM 256
#define CZ 128
#define H 8
#define C 32
#define HC 256

typedef __attribute__((ext_vector_type(8))) short short8v;
typedef __attribute__((ext_vector_type(4))) float f32x4;

#define GLOBAL_LOAD_LDS16(gsrc, ldst)                                          \
  __builtin_amdgcn_global_load_lds(                                            \
      (const __attribute__((address_space(1))) void*)(gsrc),                   \
      (__attribute__((address_space(3))) void*)(ldst), 16, 0, 0)

// ---------------------------------------------------------------------------
// Kernel 0: weight prep. Wcat_t[n][k] = bf16(Wv[k][n]) (n<256) / Wg[k][n-256];
// Wp_t[n][k] = bf16(Wp[k][n]).  B^T layouts for MFMA B-fragments.
// ---------------------------------------------------------------------------
__global__ __launch_bounds__(256) void k_prep(
    const float* __restrict__ Wv, const float* __restrict__ Wg, const float* __restrict__ Wp,
    __hip_bfloat16* __restrict__ Wcat_t, __hip_bfloat16* __restrict__ Wp_t)
{
  const int k = blockIdx.x;   // 256
  const int n = threadIdx.x;  // 256
  Wcat_t[(size_t)n * CM + k]        = __float2bfloat16(Wv[(size_t)k * HC + n]);
  Wcat_t[(size_t)(n + HC) * CM + k] = __float2bfloat16(Wg[(size_t)k * HC + n]);
  Wp_t[(size_t)n * CM + k]          = __float2bfloat16(Wp[(size_t)k * CM + n]);
}

// ---------------------------------------------------------------------------
// Kernel 1: row LayerNorm of msa -> bf16 [131072][256]. One wave per row.
// ---------------------------------------------------------------------------
__global__ __launch_bounds__(256) void k_ln(
    const float* __restrict__ msa, const float* __restrict__ gamma, const float* __restrict__ beta,
    __hip_bfloat16* __restrict__ mbf)
{
  const int t = threadIdx.x, wav = t >> 6, lane = t & 63;
  const size_t row = (size_t)blockIdx.x * 4 + wav;
  const int k0 = lane * 4;
  const float4 xv = *(const float4*)(msa + row * CM + k0);
  float s  = xv.x + xv.y + xv.z + xv.w;
  float s2 = xv.x * xv.x + xv.y * xv.y + xv.z * xv.z + xv.w * xv.w;
#pragma unroll
  for (int off = 32; off > 0; off >>= 1) {
    s  += __shfl_xor(s, off);
    s2 += __shfl_xor(s2, off);
  }
  const float mu = s * (1.f / CM);
  const float rstd = rsqrtf(s2 * (1.f / CM) - mu * mu + 1e-5f);
  const float4 gm = *(const float4*)(gamma + k0);
  const float4 bt = *(const float4*)(beta + k0);
  union { __hip_bfloat16 b[4]; short4 v; } pk;
  pk.b[0] = __float2bfloat16((xv.x - mu) * rstd * gm.x + bt.x);
  pk.b[1] = __float2bfloat16((xv.y - mu) * rstd * gm.y + bt.y);
  pk.b[2] = __float2bfloat16((xv.z - mu) * rstd * gm.z + bt.z);
  pk.b[3] = __float2bfloat16((xv.w - mu) * rstd * gm.w + bt.w);
  *(short4*)(mbf + row * CM + k0) = pk.v;
}

// ---------------------------------------------------------------------------
// Kernel 2 (MFMA, 256x128 tile, 512 thr, BK=32 double-buffer, XCD-chunked):
// D = mbf @ Wcat + bias.  T3-minimum pipeline: stage(next) issued BEFORE
// compute(cur), ONE __syncthreads() per K-step (its vmcnt(0) drain lands a
// full compute-phase after issue).  LDS 48KB total (same as r10 single-buf).
// ---------------------------------------------------------------------------
__global__ __launch_bounds__(512) void k_mm1(
    const __hip_bfloat16* __restrict__ mbf, const __hip_bfloat16* __restrict__ Wcat_t,
    const float* __restrict__ bv, const float* __restrict__ bg,
    __hip_bfloat16* __restrict__ vc, __hip_bfloat16* __restrict__ gb)
{
  __shared__ __hip_bfloat16 Ac[2][4 * 256 * 8];  // 2 x 16 KB [kb][mrow][kr]
  __shared__ __hip_bfloat16 Bc[2][4 * 128 * 8];  // 2 x 8 KB  [kb][nrow][kr]
  const int t = threadIdx.x;
  const int wave = t >> 6, lane = t & 63;
  const int wm = wave >> 1, wn = wave & 1;     // 4m x 2n
  const int lr = lane & 15, lq = lane >> 4;
  const int bid = blockIdx.x;
  const int virt = (bid & 7) * 256 + (bid >> 3);
  const int n0 = (virt & 3) * 128;
  const int m0 = (virt >> 2) * 256;
  const bool vhalf = (n0 < HC);

  float bias[4];
#pragma unroll
  for (int ni = 0; ni < 4; ++ni) {
    const int col = n0 + wn * 64 + ni * 16 + lr;
    bias[ni] = vhalf ? bv[col] : bg[col - HC];
  }
  f32x4 acc[4][4];
#pragma unroll
  for (int mi = 0; mi < 4; ++mi)
#pragma unroll
    for (int ni = 0; ni < 4; ++ni) acc[mi][ni] = (f32x4)bias[ni];

  auto stage = [&](int p, int kt) {
#pragma unroll
    for (int u = 0; u < 2; ++u) {       // A: 16 chunks over 8 waves
      const int cc = wave * 2 + u;
      const int kb = cc & 3, ih = cc >> 2;   // kb 0..3, ih 0..3
      GLOBAL_LOAD_LDS16(mbf + ((size_t)(m0 + ih * 64 + lane)) * CM + kt * 32 + kb * 8,
                        &Ac[p][(kb * 256 + ih * 64 + lane) * 8]);
    }
    {                                    // B: 8 chunks over 8 waves
      const int kb = wave & 3, ih = wave >> 2;  // kb 0..3, ih 0..1
      GLOBAL_LOAD_LDS16(Wcat_t + ((size_t)(n0 + ih * 64 + lane)) * CM + kt * 32 + kb * 8,
                        &Bc[p][(kb * 128 + ih * 64 + lane) * 8]);
    }
  };
  auto compute = [&](int p) {
    short8v a[4], b[4];
#pragma unroll
    for (int mi = 0; mi < 4; ++mi)
      a[mi] = *(const short8v*)&Ac[p][((lq * 256) + wm * 64 + mi * 16 + lr) * 8];
#pragma unroll
    for (int ni = 0; ni < 4; ++ni)
      b[ni] = *(const short8v*)&Bc[p][((lq * 128) + wn * 64 + ni * 16 + lr) * 8];
#pragma unroll
    for (int mi = 0; mi < 4; ++mi)
#pragma unroll
      for (int ni = 0; ni < 4; ++ni)
        acc[mi][ni] = __builtin_amdgcn_mfma_f32_16x16x32_bf16(a[mi], b[ni], acc[mi][ni], 0, 0, 0);
  };

  const int NT = CM / 32;  // 8
  stage(0, 0);
  __syncthreads();
  int cur = 0;
  for (int kt = 0; kt < NT; ++kt) {
    if (kt + 1 < NT) stage(cur ^ 1, kt + 1);  // issue next-tile loads FIRST
    compute(cur);                             // ds_read + MFMA on current
    __syncthreads();                          // vmcnt(0)+lgkmcnt(0)+barrier
    cur ^= 1;
  }

  if (vhalf) {  // v -> chunked layout, 4 consecutive j per lane = 8B store
#pragma unroll
    for (int mi = 0; mi < 4; ++mi) {
      const int rowb = m0 + wm * 64 + mi * 16 + lq * 4;
      const int s = rowb >> 9;
      const int j = rowb & (N - 1);
      const int jb = j >> 3, jlo = (lq & 1) * 4;
#pragma unroll
      for (int ni = 0; ni < 4; ++ni) {
        const int col = n0 + wn * 64 + ni * 16 + lr;
        const int h = col >> 5, c = col & 31;
        union { __hip_bfloat16 b[4]; short4 v; } pk;
#pragma unroll
        for (int r = 0; r < 4; ++r) pk.b[r] = __float2bfloat16(acc[mi][ni][r]);
        *(short4*)(vc + ((size_t)(h * (N / 8) + jb) * (S * C) + s * C + c) * 8 + jlo) = pk.v;
      }
    }
  } else {  // g half
#pragma unroll
    for (int mi = 0; mi < 4; ++mi) {
      const int rowb = m0 + wm * 64 + mi * 16 + lq * 4;
#pragma unroll
      for (int ni = 0; ni < 4; ++ni) {
        const int colp = (n0 - HC) + wn * 64 + ni * 16 + lr;
#pragma unroll
        for (int r = 0; r < 4; ++r)
          gb[(size_t)(rowb + r) * HC + colp] =
              __float2bfloat16(1.f / (1.f + __expf(-acc[mi][ni][r])));
      }
    }
  }
}

// ---------------------------------------------------------------------------
// Kernel 3 (fused): LayerNorm(pair) @ Wb -> softmax over j -> wbh [h][i][j].
// ---------------------------------------------------------------------------
__global__ __launch_bounds__(256) void k_lnb_sm(
    const float* __restrict__ pair, const float* __restrict__ gamma, const float* __restrict__ beta,
    const float* __restrict__ Wb, __hip_bfloat16* __restrict__ wbh)
{
  __shared__ float slog[H][N];  // 16 KB
  const int t = threadIdx.x, wav = t >> 6, lane = t & 63;
  const int q = lane & 15, sub = lane >> 4;  // 4 rows per wave per iter
  const int k0 = q * 8;
  const size_t i = blockIdx.x;

  float wreg[8][8];
#pragma unroll
  for (int kk = 0; kk < 8; ++kk) {
    *(float4*)&wreg[kk][0] = *(const float4*)&Wb[(k0 + kk) * H];
    *(float4*)&wreg[kk][4] = *(const float4*)&Wb[(k0 + kk) * H + 4];
  }
  const float4 gm0 = *(const float4*)(gamma + k0);
  const float4 gm1 = *(const float4*)(gamma + k0 + 4);
  const float4 bt0 = *(const float4*)(beta + k0);
  const float4 bt1 = *(const float4*)(beta + k0 + 4);

#pragma unroll 2
  for (int it = 0; it < 32; ++it) {
    const int j = it * 16 + wav * 4 + sub;
    const float* x = pair + (i * N + j) * CZ + k0;
    const float4 x0 = *(const float4*)(x);
    const float4 x1 = *(const float4*)(x + 4);

    float s  = x0.x + x0.y + x0.z + x0.w + x1.x + x1.y + x1.z + x1.w;
    float s2 = x0.x * x0.x + x0.y * x0.y + x0.z * x0.z + x0.w * x0.w
             + x1.x * x1.x + x1.y * x1.y + x1.z * x1.z + x1.w * x1.w;
#pragma unroll
    for (int off = 8; off > 0; off >>= 1) {
      s  += __shfl_xor(s, off);
      s2 += __shfl_xor(s2, off);
    }
    const float mu = s * (1.f / CZ);
    const float rstd = rsqrtf(s2 * (1.f / CZ) - mu * mu + 1e-5f);

    float xn[8];
    xn[0] = (x0.x - mu) * rstd * gm0.x + bt0.x;
    xn[1] = (x0.y - mu) * rstd * gm0.y + bt0.y;
    xn[2] = (x0.z - mu) * rstd * gm0.z + bt0.z;
    xn[3] = (x0.w - mu) * rstd * gm0.w + bt0.w;
    xn[4] = (x1.x - mu) * rstd * gm1.x + bt1.x;
    xn[5] = (x1.y - mu) * rstd * gm1.y + bt1.y;
    xn[6] = (x1.z - mu) * rstd * gm1.z + bt1.z;
    xn[7] = (x1.w - mu) * rstd * gm1.w + bt1.w;

    float acc[8];
#pragma unroll
    for (int h = 0; h < 8; ++h) acc[h] = 0.f;
#pragma unroll
    for (int kk = 0; kk < 8; ++kk)
#pragma unroll
      for (int h = 0; h < 8; ++h) acc[h] += xn[kk] * wreg[kk][h];

#pragma unroll
    for (int h = 0; h < 8; ++h) {
#pragma unroll
      for (int off = 8; off > 0; off >>= 1) acc[h] += __shfl_xor(acc[h], off);
    }
    if (q == 0) {
#pragma unroll
      for (int h = 0; h < 8; ++h) slog[h][j] = acc[h];
    }
  }
  __syncthreads();

#pragma unroll
  for (int hh2 = 0; hh2 < 2; ++hh2) {
    const int hh = wav * 2 + hh2;
    const int j0 = lane * 8;
    const float4 p0 = *(const float4*)&slog[hh][j0];
    const float4 p1 = *(const float4*)&slog[hh][j0 + 4];
    float mx = fmaxf(fmaxf(fmaxf(p0.x, p0.y), fmaxf(p0.z, p0.w)),
                     fmaxf(fmaxf(p1.x, p1.y), fmaxf(p1.z, p1.w)));
#pragma unroll
    for (int off = 32; off > 0; off >>= 1) mx = fmaxf(mx, __shfl_xor(mx, off));
    float e[8];
    e[0] = __expf(p0.x - mx); e[1] = __expf(p0.y - mx);
    e[2] = __expf(p0.z - mx); e[3] = __expf(p0.w - mx);
    e[4] = __expf(p1.x - mx); e[5] = __expf(p1.y - mx);
    e[6] = __expf(p1.z - mx); e[7] = __expf(p1.w - mx);
    float sum = ((e[0] + e[1]) + (e[2] + e[3])) + ((e[4] + e[5]) + (e[6] + e[7]));
#pragma unroll
    for (int off = 32; off > 0; off >>= 1) sum += __shfl_xor(sum, off);
    const float inv = 1.f / sum;
    union { __hip_bfloat16 b[8]; short8v v; } pk;
#pragma unroll
    for (int r = 0; r < 8; ++r) pk.b[r] = __float2bfloat16(e[r] * inv);
    *(short8v*)(wbh + ((size_t)hh * N + i) * N + j0) = pk.v;
  }
}

// ---------------------------------------------------------------------------
// Kernel 5 (MFMA, 256x128 tile, 512 thr, BK=32 double-buffer, XCD-chunked):
// per h, O[i][(s,c)] = W_h[i][j] x V_h[j][(s,c)], gate RMW epilogue.
// ---------------------------------------------------------------------------
__global__ __launch_bounds__(512) void k_attn_mfma(
    const __hip_bfloat16* __restrict__ vc, const __hip_bfloat16* __restrict__ wbh,
    __hip_bfloat16* gb)
{
  __shared__ __hip_bfloat16 Ac[2][4 * 256 * 8];  // 2 x 16 KB [kb][irow][jr]
  __shared__ __hip_bfloat16 Bc[2][4 * 128 * 8];  // 2 x 8 KB  [kb][nrow][jr]

  const int t = threadIdx.x;
  const int wave = t >> 6, lane = t & 63;
  const int wm = wave >> 1, wn = wave & 1;
  const int lr = lane & 15, lq = lane >> 4;
  const int bid = blockIdx.x;
  const int virt = (bid & 7) * 128 + (bid >> 3);
  const int h  = virt >> 7;
  const int w_ = virt & 127;
  const int i0 = (w_ >> 6) * 256;
  const int n0 = (w_ & 63) * 128;

  f32x4 acc[4][4];
#pragma unroll
  for (int mi = 0; mi < 4; ++mi)
#pragma unroll
    for (int ni = 0; ni < 4; ++ni) acc[mi][ni] = (f32x4)0.f;

  const __hip_bfloat16* Abase = wbh + ((size_t)h * N + i0) * N;
  const __hip_bfloat16* Bbase = vc + (size_t)h * (N / 8) * (S * C) * 8 + (size_t)n0 * 8;

  auto stage = [&](int p, int kt) {
#pragma unroll
    for (int u = 0; u < 2; ++u) {       // A: 16 chunks
      const int cc = wave * 2 + u;
      const int kb = cc & 3, ih = cc >> 2;
      GLOBAL_LOAD_LDS16(Abase + ((size_t)(ih * 64 + lane)) * N + kt * 32 + kb * 8,
                        &Ac[p][(kb * 256 + ih * 64 + lane) * 8]);
    }
    {                                    // B: 8 chunks
      const int kb = wave & 3, ih = wave >> 2;
      GLOBAL_LOAD_LDS16(Bbase + ((size_t)(kt * 4 + kb) * (S * C) + ih * 64 + lane) * 8,
                        &Bc[p][(kb * 128 + ih * 64 + lane) * 8]);
    }
  };
  auto compute = [&](int p) {
    short8v a[4], b[4];
#pragma unroll
    for (int mi = 0; mi < 4; ++mi)
      a[mi] = *(const short8v*)&Ac[p][((lq * 256) + wm * 64 + mi * 16 + lr) * 8];
#pragma unroll
    for (int ni = 0; ni < 4; ++ni)
      b[ni] = *(const short8v*)&Bc[p][((lq * 128) + wn * 64 + ni * 16 + lr) * 8];
#pragma unroll
    for (int mi = 0; mi < 4; ++mi)
#pragma unroll
      for (int ni = 0; ni < 4; ++ni)
        acc[mi][ni] = __builtin_amdgcn_mfma_f32_16x16x32_bf16(a[mi], b[ni], acc[mi][ni], 0, 0, 0);
  };

  const int NT = N / 32;  // 16
  stage(0, 0);
  __syncthreads();
  int cur = 0;
  for (int kt = 0; kt < NT; ++kt) {
    if (kt + 1 < NT) stage(cur ^ 1, kt + 1);
    compute(cur);
    __syncthreads();
    cur ^= 1;
  }

  // epilogue: gate RMW (r10-proven mapping)
#pragma unroll
  for (int mi = 0; mi < 4; ++mi)
#pragma unroll
    for (int ni = 0; ni < 4; ++ni) {
      const int n = n0 + wn * 64 + ni * 16 + lr;
      const int sidx = n >> 5, c = n & 31;
#pragma unroll
      for (int r = 0; r < 4; ++r) {
        const int i = i0 + wm * 64 + mi * 16 + lq * 4 + r;
        const size_t idx = (((size_t)sidx * N + i) << 8) + h * C + c;
        const float gv = __bfloat162float(gb[idx]);
        gb[idx] = __float2bfloat16(gv * acc[mi][ni][r]);
      }
    }
}

// ---------------------------------------------------------------------------
// Kernel 6 (MFMA, 256x128 tile, 512 thr, BK=32 double-buffer, XCD-chunked):
// out = og @ Wp, fp32 out.
// ---------------------------------------------------------------------------
__global__ __launch_bounds__(512) void k_out_mfma(
    const __hip_bfloat16* __restrict__ ogb, const __hip_bfloat16* __restrict__ Wp_t,
    float* __restrict__ out)
{
  __shared__ __hip_bfloat16 Ac[2][4 * 256 * 8];  // 2 x 16 KB
  __shared__ __hip_bfloat16 Bc[2][4 * 128 * 8];  // 2 x 8 KB
  const int t = threadIdx.x;
  const int wave = t >> 6, lane = t & 63;
  const int wm = wave >> 1, wn = wave & 1;
  const int lr = lane & 15, lq = lane >> 4;
  const int bid = blockIdx.x;
  const int virt = (bid & 7) * 128 + (bid >> 3);
  const int n0 = (virt & 1) * 128;
  const int m0 = (virt >> 1) * 256;

  f32x4 acc[4][4];
#pragma unroll
  for (int mi = 0; mi < 4; ++mi)
#pragma unroll
    for (int ni = 0; ni < 4; ++ni) acc[mi][ni] = (f32x4)0.f;

  auto stage = [&](int p, int kt) {
#pragma unroll
    for (int u = 0; u < 2; ++u) {
      const int cc = wave * 2 + u;
      const int kb = cc & 3, ih = cc >> 2;
      GLOBAL_LOAD_LDS16(ogb + ((size_t)(m0 + ih * 64 + lane)) * CM + kt * 32 + kb * 8,
                        &Ac[p][(kb * 256 + ih * 64 + lane) * 8]);
    }
    {
      const int kb = wave & 3, ih = wave >> 2;
      GLOBAL_LOAD_LDS16(Wp_t + ((size_t)(n0 + ih * 64 + lane)) * CM + kt * 32 + kb * 8,
                        &Bc[p][(kb * 128 + ih * 64 + lane) * 8]);
    }
  };
  auto compute = [&](int p) {
    short8v a[4], b[4];
#pragma unroll
    for (int mi = 0; mi < 4; ++mi)
      a[mi] = *(const short8v*)&Ac[p][((lq * 256) + wm * 64 + mi * 16 + lr) * 8];
#pragma unroll
    for (int ni = 0; ni < 4; ++ni)
      b[ni] = *(const short8v*)&Bc[p][((lq * 128) + wn * 64 + ni * 16 + lr) * 8];
#pragma unroll
    for (int mi = 0; mi < 4; ++mi)
#pragma unroll
      for (int ni = 0; ni < 4; ++ni)
        acc[mi][ni] = __builtin_amdgcn_mfma_f32_16x16x32_bf16(a[mi], b[ni], acc[mi][ni], 0, 0, 0);
  };

  const int NT = CM / 32;  // 8
  stage(0, 0);
  __syncthreads();
  int cur = 0;
  for (int kt = 0; kt < NT; ++kt) {
    if (kt + 1 < NT) stage(cur ^ 1, kt + 1);
    compute(cur);
    __syncthreads();
    cur ^= 1;
  }

#pragma unroll
  for (int mi = 0; mi < 4; ++mi) {
    const int rowb = m0 + wm * 64 + mi * 16 + lq * 4;
#pragma unroll
    for (int ni = 0; ni < 4; ++ni) {
      const int col = n0 + wn * 64 + ni * 16 + lr;
#pragma unroll
      for (int r = 0; r < 4; ++r)
        out[(size_t)(rowb + r) * CM + col] = acc[mi][ni][r];
    }
  }
}

// ---------------------------------------------------------------------------
extern "C" void kernel_launch(void* const* d_in, const int* in_sizes, int n_in,
                              void* d_out, int out_size, void* d_ws, size_t ws_size,
                              hipStream_t stream)
{
  const float* msa      = (const float*)d_in[0];
  const float* pair     = (const float*)d_in[1];
  const float* ln_msa_g = (const float*)d_in[2];
  const float* ln_msa_b = (const float*)d_in[3];
  const float* Wv       = (const float*)d_in[4];
  const float* bv       = (const float*)d_in[5];
  const float* ln_z_g   = (const float*)d_in[6];
  const float* ln_z_b   = (const float*)d_in[7];
  const float* Wb       = (const float*)d_in[8];
  const float* bb       = (const float*)d_in[9];
  const float* Wg       = (const float*)d_in[10];
  const float* bg       = (const float*)d_in[11];
  const float* Wp       = (const float*)d_in[12];
  float* out = (float*)d_out;
  (void)bb;  // softmax is shift-invariant; bb cancels

  // ws layout (bytes)
  char* w = (char*)d_ws;
  __hip_bfloat16* vc     = (__hip_bfloat16*)(w);                     // 67.1 MB [h][j/8][s*32+c][j%8]
  __hip_bfloat16* mbf    = (__hip_bfloat16*)(w + 67108864);          // 67.1 MB [row][k]
  __hip_bfloat16* gb     = (__hip_bfloat16*)(w + 134217728);         // 67.1 MB [row][h*32+c] (g, then og)
  __hip_bfloat16* wbh    = (__hip_bfloat16*)(w + 209715200);         //  4.2 MB [h][i][j] bf16
  __hip_bfloat16* Wcat_t = (__hip_bfloat16*)(w + 213909504);         //  256 KB [n][k]
  __hip_bfloat16* Wp_t   = (__hip_bfloat16*)(w + 214171648);         //  128 KB [n][k]

  k_prep<<<256, 256, 0, stream>>>(Wv, Wg, Wp, Wcat_t, Wp_t);
  k_ln<<<S * N / 4, 256, 0, stream>>>(msa, ln_msa_g, ln_msa_b, mbf);
  k_mm1<<<2048, 512, 0, stream>>>(mbf, Wcat_t, bv, bg, vc, gb);
  k_lnb_sm<<<N, 256, 0, stream>>>(pair, ln_z_g, ln_z_b, Wb, wbh);
  k_attn_mfma<<<1024, 512, 0, stream>>>(vc, wbh, gb);
  k_out_mfma<<<1024, 512, 0, stream>>>(gb, Wp_t, out);
}

// Round 14
// 341.400 us; speedup vs baseline: 1.0701x; 1.0701x over previous
//
#include <hip/hip_runtime.h>
#include <hip/hip_bf16.h>
#include <math.h>

#define S 256
#define N 512
#define CM 256
#define CZ 128
#define H 8
#define C 32
#define HC 256

typedef __attribute__((ext_vector_type(8))) short short8v;
typedef __attribute__((ext_vector_type(4))) float f32x4;

#define GLOBAL_LOAD_LDS16(gsrc, ldst)                                          \
  __builtin_amdgcn_global_load_lds(                                            \
      (const __attribute__((address_space(1))) void*)(gsrc),                   \
      (__attribute__((address_space(3))) void*)(ldst), 16, 0, 0)

// ---------------------------------------------------------------------------
// Kernel 0: weight prep. Wcat_t[n][k] = bf16(Wv[k][n]) (n<256) / Wg[k][n-256];
// Wp_t[n][k] = bf16(Wp[k][n]).  B^T layouts for MFMA B-fragments.
// ---------------------------------------------------------------------------
__global__ __launch_bounds__(256) void k_prep(
    const float* __restrict__ Wv, const float* __restrict__ Wg, const float* __restrict__ Wp,
    __hip_bfloat16* __restrict__ Wcat_t, __hip_bfloat16* __restrict__ Wp_t)
{
  const int k = blockIdx.x;   // 256
  const int n = threadIdx.x;  // 256
  Wcat_t[(size_t)n * CM + k]        = __float2bfloat16(Wv[(size_t)k * HC + n]);
  Wcat_t[(size_t)(n + HC) * CM + k] = __float2bfloat16(Wg[(size_t)k * HC + n]);
  Wp_t[(size_t)n * CM + k]          = __float2bfloat16(Wp[(size_t)k * CM + n]);
}

// ---------------------------------------------------------------------------
// Kernel 1: row LayerNorm of msa -> bf16 [131072][256]. One wave per row.
// ---------------------------------------------------------------------------
__global__ __launch_bounds__(256) void k_ln(
    const float* __restrict__ msa, const float* __restrict__ gamma, const float* __restrict__ beta,
    __hip_bfloat16* __restrict__ mbf)
{
  const int t = threadIdx.x, wav = t >> 6, lane = t & 63;
  const size_t row = (size_t)blockIdx.x * 4 + wav;
  const int k0 = lane * 4;
  const float4 xv = *(const float4*)(msa + row * CM + k0);
  float s  = xv.x + xv.y + xv.z + xv.w;
  float s2 = xv.x * xv.x + xv.y * xv.y + xv.z * xv.z + xv.w * xv.w;
#pragma unroll
  for (int off = 32; off > 0; off >>= 1) {
    s  += __shfl_xor(s, off);
    s2 += __shfl_xor(s2, off);
  }
  const float mu = s * (1.f / CM);
  const float rstd = rsqrtf(s2 * (1.f / CM) - mu * mu + 1e-5f);
  const float4 gm = *(const float4*)(gamma + k0);
  const float4 bt = *(const float4*)(beta + k0);
  union { __hip_bfloat16 b[4]; short4 v; } pk;
  pk.b[0] = __float2bfloat16((xv.x - mu) * rstd * gm.x + bt.x);
  pk.b[1] = __float2bfloat16((xv.y - mu) * rstd * gm.y + bt.y);
  pk.b[2] = __float2bfloat16((xv.z - mu) * rstd * gm.z + bt.z);
  pk.b[3] = __float2bfloat16((xv.w - mu) * rstd * gm.w + bt.w);
  *(short4*)(mbf + row * CM + k0) = pk.v;
}

// ---------------------------------------------------------------------------
// Kernel 2 (MFMA, 256x128 tile, 512 thr, single-buffer, XCD-chunked):
// D = mbf @ Wcat + bias.  (r10-exact, best measured.)
// ---------------------------------------------------------------------------
__global__ __launch_bounds__(512) void k_mm1(
    const __hip_bfloat16* __restrict__ mbf, const __hip_bfloat16* __restrict__ Wcat_t,
    const float* __restrict__ bv, const float* __restrict__ bg,
    __hip_bfloat16* __restrict__ vc, __hip_bfloat16* __restrict__ gb)
{
  __shared__ __hip_bfloat16 Ac[8 * 256 * 8];  // 32 KB [kb][mrow][kr]
  __shared__ __hip_bfloat16 Bc[8 * 128 * 8];  // 16 KB [kb][nrow][kr]
  const int t = threadIdx.x;
  const int wave = t >> 6, lane = t & 63;
  const int wm = wave >> 1, wn = wave & 1;     // 4m x 2n
  const int lr = lane & 15, lq = lane >> 4;
  const int bid = blockIdx.x;
  const int virt = (bid & 7) * 256 + (bid >> 3);
  const int n0 = (virt & 3) * 128;
  const int m0 = (virt >> 2) * 256;
  const bool vhalf = (n0 < HC);

  float bias[4];
#pragma unroll
  for (int ni = 0; ni < 4; ++ni) {
    const int col = n0 + wn * 64 + ni * 16 + lr;
    bias[ni] = vhalf ? bv[col] : bg[col - HC];
  }
  f32x4 acc[4][4];
#pragma unroll
  for (int mi = 0; mi < 4; ++mi)
#pragma unroll
    for (int ni = 0; ni < 4; ++ni) acc[mi][ni] = (f32x4)bias[ni];

  for (int kt = 0; kt < CM / 64; ++kt) {
    __syncthreads();
#pragma unroll
    for (int u = 0; u < 4; ++u) {       // A: 32 chunks of 1KB
      const int cc = wave * 4 + u;
      const int kb = cc & 7, ih = cc >> 3;
      GLOBAL_LOAD_LDS16(mbf + ((size_t)(m0 + ih * 64 + lane)) * CM + kt * 64 + kb * 8,
                        &Ac[(kb * 256 + ih * 64 + lane) * 8]);
    }
#pragma unroll
    for (int u = 0; u < 2; ++u) {       // B: 16 chunks
      const int cc = wave * 2 + u;
      const int kb = cc & 7, ih = cc >> 3;
      GLOBAL_LOAD_LDS16(Wcat_t + ((size_t)(n0 + ih * 64 + lane)) * CM + kt * 64 + kb * 8,
                        &Bc[(kb * 128 + ih * 64 + lane) * 8]);
    }
    __syncthreads();
#pragma unroll
    for (int kh = 0; kh < 2; ++kh) {
      const int ldb = lq + kh * 4;
      short8v a[4], b[4];
#pragma unroll
      for (int mi = 0; mi < 4; ++mi)
        a[mi] = *(const short8v*)&Ac[((ldb * 256) + wm * 64 + mi * 16 + lr) * 8];
#pragma unroll
      for (int ni = 0; ni < 4; ++ni)
        b[ni] = *(const short8v*)&Bc[((ldb * 128) + wn * 64 + ni * 16 + lr) * 8];
#pragma unroll
      for (int mi = 0; mi < 4; ++mi)
#pragma unroll
        for (int ni = 0; ni < 4; ++ni)
          acc[mi][ni] = __builtin_amdgcn_mfma_f32_16x16x32_bf16(a[mi], b[ni], acc[mi][ni], 0, 0, 0);
    }
  }

  if (vhalf) {  // v -> chunked layout, 4 consecutive j per lane = 8B store
#pragma unroll
    for (int mi = 0; mi < 4; ++mi) {
      const int rowb = m0 + wm * 64 + mi * 16 + lq * 4;
      const int s = rowb >> 9;
      const int j = rowb & (N - 1);
      const int jb = j >> 3, jlo = (lq & 1) * 4;
#pragma unroll
      for (int ni = 0; ni < 4; ++ni) {
        const int col = n0 + wn * 64 + ni * 16 + lr;
        const int h = col >> 5, c = col & 31;
        union { __hip_bfloat16 b[4]; short4 v; } pk;
#pragma unroll
        for (int r = 0; r < 4; ++r) pk.b[r] = __float2bfloat16(acc[mi][ni][r]);
        *(short4*)(vc + ((size_t)(h * (N / 8) + jb) * (S * C) + s * C + c) * 8 + jlo) = pk.v;
      }
    }
  } else {  // g half
#pragma unroll
    for (int mi = 0; mi < 4; ++mi) {
      const int rowb = m0 + wm * 64 + mi * 16 + lq * 4;
#pragma unroll
      for (int ni = 0; ni < 4; ++ni) {
        const int colp = (n0 - HC) + wn * 64 + ni * 16 + lr;
#pragma unroll
        for (int r = 0; r < 4; ++r)
          gb[(size_t)(rowb + r) * HC + colp] =
              __float2bfloat16(1.f / (1.f + __expf(-acc[mi][ni][r])));
      }
    }
  }
}

// ---------------------------------------------------------------------------
// Kernel 3 (fused): LayerNorm(pair) @ Wb -> softmax over j -> wbh [h][i][j].
// ---------------------------------------------------------------------------
__global__ __launch_bounds__(256) void k_lnb_sm(
    const float* __restrict__ pair, const float* __restrict__ gamma, const float* __restrict__ beta,
    const float* __restrict__ Wb, __hip_bfloat16* __restrict__ wbh)
{
  __shared__ float slog[H][N];  // 16 KB
  const int t = threadIdx.x, wav = t >> 6, lane = t & 63;
  const int q = lane & 15, sub = lane >> 4;  // 4 rows per wave per iter
  const int k0 = q * 8;
  const size_t i = blockIdx.x;

  float wreg[8][8];
#pragma unroll
  for (int kk = 0; kk < 8; ++kk) {
    *(float4*)&wreg[kk][0] = *(const float4*)&Wb[(k0 + kk) * H];
    *(float4*)&wreg[kk][4] = *(const float4*)&Wb[(k0 + kk) * H + 4];
  }
  const float4 gm0 = *(const float4*)(gamma + k0);
  const float4 gm1 = *(const float4*)(gamma + k0 + 4);
  const float4 bt0 = *(const float4*)(beta + k0);
  const float4 bt1 = *(const float4*)(beta + k0 + 4);

#pragma unroll 2
  for (int it = 0; it < 32; ++it) {
    const int j = it * 16 + wav * 4 + sub;
    const float* x = pair + (i * N + j) * CZ + k0;
    const float4 x0 = *(const float4*)(x);
    const float4 x1 = *(const float4*)(x + 4);

    float s  = x0.x + x0.y + x0.z + x0.w + x1.x + x1.y + x1.z + x1.w;
    float s2 = x0.x * x0.x + x0.y * x0.y + x0.z * x0.z + x0.w * x0.w
             + x1.x * x1.x + x1.y * x1.y + x1.z * x1.z + x1.w * x1.w;
#pragma unroll
    for (int off = 8; off > 0; off >>= 1) {
      s  += __shfl_xor(s, off);
      s2 += __shfl_xor(s2, off);
    }
    const float mu = s * (1.f / CZ);
    const float rstd = rsqrtf(s2 * (1.f / CZ) - mu * mu + 1e-5f);

    float xn[8];
    xn[0] = (x0.x - mu) * rstd * gm0.x + bt0.x;
    xn[1] = (x0.y - mu) * rstd * gm0.y + bt0.y;
    xn[2] = (x0.z - mu) * rstd * gm0.z + bt0.z;
    xn[3] = (x0.w - mu) * rstd * gm0.w + bt0.w;
    xn[4] = (x1.x - mu) * rstd * gm1.x + bt1.x;
    xn[5] = (x1.y - mu) * rstd * gm1.y + bt1.y;
    xn[6] = (x1.z - mu) * rstd * gm1.z + bt1.z;
    xn[7] = (x1.w - mu) * rstd * gm1.w + bt1.w;

    float acc[8];
#pragma unroll
    for (int h = 0; h < 8; ++h) acc[h] = 0.f;
#pragma unroll
    for (int kk = 0; kk < 8; ++kk)
#pragma unroll
      for (int h = 0; h < 8; ++h) acc[h] += xn[kk] * wreg[kk][h];

#pragma unroll
    for (int h = 0; h < 8; ++h) {
#pragma unroll
      for (int off = 8; off > 0; off >>= 1) acc[h] += __shfl_xor(acc[h], off);
    }
    if (q == 0) {
#pragma unroll
      for (int h = 0; h < 8; ++h) slog[h][j] = acc[h];
    }
  }
  __syncthreads();

#pragma unroll
  for (int hh2 = 0; hh2 < 2; ++hh2) {
    const int hh = wav * 2 + hh2;
    const int j0 = lane * 8;
    const float4 p0 = *(const float4*)&slog[hh][j0];
    const float4 p1 = *(const float4*)&slog[hh][j0 + 4];
    float mx = fmaxf(fmaxf(fmaxf(p0.x, p0.y), fmaxf(p0.z, p0.w)),
                     fmaxf(fmaxf(p1.x, p1.y), fmaxf(p1.z, p1.w)));
#pragma unroll
    for (int off = 32; off > 0; off >>= 1) mx = fmaxf(mx, __shfl_xor(mx, off));
    float e[8];
    e[0] = __expf(p0.x - mx); e[1] = __expf(p0.y - mx);
    e[2] = __expf(p0.z - mx); e[3] = __expf(p0.w - mx);
    e[4] = __expf(p1.x - mx); e[5] = __expf(p1.y - mx);
    e[6] = __expf(p1.z - mx); e[7] = __expf(p1.w - mx);
    float sum = ((e[0] + e[1]) + (e[2] + e[3])) + ((e[4] + e[5]) + (e[6] + e[7]));
#pragma unroll
    for (int off = 32; off > 0; off >>= 1) sum += __shfl_xor(sum, off);
    const float inv = 1.f / sum;
    union { __hip_bfloat16 b[8]; short8v v; } pk;
#pragma unroll
    for (int r = 0; r < 8; ++r) pk.b[r] = __float2bfloat16(e[r] * inv);
    *(short8v*)(wbh + ((size_t)hh * N + i) * N + j0) = pk.v;
  }
}

// ---------------------------------------------------------------------------
// Kernel 5 (MFMA, 256x128 tile, 512 thr, BK=32 COUNTED-VMCNT 2-deep pipeline,
// XCD-chunked): per h, O[i][(s,c)] = W_h[i][j] x V_h[j][(s,c)], gate RMW.
// T4 invariant: per-wave outstanding loads oscillate 6->3->6, NEVER 0 in the
// main loop.  stage/compute bodies identical to r13 (numerically verified);
// only the pipeline control flow differs.
// ---------------------------------------------------------------------------
__global__ __launch_bounds__(512) void k_attn_mfma(
    const __hip_bfloat16* __restrict__ vc, const __hip_bfloat16* __restrict__ wbh,
    __hip_bfloat16* gb)
{
  __shared__ __hip_bfloat16 Ac[2][4 * 256 * 8];  // 2 x 16 KB [kb][irow][jr]
  __shared__ __hip_bfloat16 Bc[2][4 * 128 * 8];  // 2 x 8 KB  [kb][nrow][jr]

  const int t = threadIdx.x;
  const int wave = t >> 6, lane = t & 63;
  const int wm = wave >> 1, wn = wave & 1;
  const int lr = lane & 15, lq = lane >> 4;
  const int bid = blockIdx.x;
  const int virt = (bid & 7) * 128 + (bid >> 3);
  const int h  = virt >> 7;
  const int w_ = virt & 127;
  const int i0 = (w_ >> 6) * 256;
  const int n0 = (w_ & 63) * 128;

  f32x4 acc[4][4];
#pragma unroll
  for (int mi = 0; mi < 4; ++mi)
#pragma unroll
    for (int ni = 0; ni < 4; ++ni) acc[mi][ni] = (f32x4)0.f;

  const __hip_bfloat16* Abase = wbh + ((size_t)h * N + i0) * N;
  const __hip_bfloat16* Bbase = vc + (size_t)h * (N / 8) * (S * C) * 8 + (size_t)n0 * 8;

  // 3 global_load_lds per wave per tile (A:2, B:1)
  auto stage = [&](int p, int kt) {
#pragma unroll
    for (int u = 0; u < 2; ++u) {       // A: 16 chunks over 8 waves
      const int cc = wave * 2 + u;
      const int kb = cc & 3, ih = cc >> 2;
      GLOBAL_LOAD_LDS16(Abase + ((size_t)(ih * 64 + lane)) * N + kt * 32 + kb * 8,
                        &Ac[p][(kb * 256 + ih * 64 + lane) * 8]);
    }
    {                                    // B: 8 chunks over 8 waves
      const int kb = wave & 3, ih = wave >> 2;
      GLOBAL_LOAD_LDS16(Bbase + ((size_t)(kt * 4 + kb) * (S * C) + ih * 64 + lane) * 8,
                        &Bc[p][(kb * 128 + ih * 64 + lane) * 8]);
    }
  };
  auto compute = [&](int p) {
    short8v a[4], b[4];
#pragma unroll
    for (int mi = 0; mi < 4; ++mi)
      a[mi] = *(const short8v*)&Ac[p][((lq * 256) + wm * 64 + mi * 16 + lr) * 8];
#pragma unroll
    for (int ni = 0; ni < 4; ++ni)
      b[ni] = *(const short8v*)&Bc[p][((lq * 128) + wn * 64 + ni * 16 + lr) * 8];
#pragma unroll
    for (int mi = 0; mi < 4; ++mi)
#pragma unroll
      for (int ni = 0; ni < 4; ++ni)
        acc[mi][ni] = __builtin_amdgcn_mfma_f32_16x16x32_bf16(a[mi], b[ni], acc[mi][ni], 0, 0, 0);
  };

  const int NT = N / 32;  // 16
  stage(0, 0);            // outstanding: 3
  stage(1, 1);            // outstanding: 6
  for (int kt = 0; kt < NT - 1; ++kt) {
    // wait ONLY for tile kt's 3 loads; tile kt+1's stay in flight
    asm volatile("s_waitcnt vmcnt(3)" ::: "memory");
    __builtin_amdgcn_s_barrier();
    __builtin_amdgcn_sched_barrier(0);
    compute(kt & 1);
    __builtin_amdgcn_s_barrier();      // all waves done reading buf kt&1
    __builtin_amdgcn_sched_barrier(0);
    if (kt + 2 < NT) stage(kt & 1, kt + 2);  // outstanding back to 6
  }
  asm volatile("s_waitcnt vmcnt(0)" ::: "memory");
  __builtin_amdgcn_s_barrier();
  __builtin_amdgcn_sched_barrier(0);
  compute((NT - 1) & 1);

  // epilogue: gate RMW (r10-proven mapping)
#pragma unroll
  for (int mi = 0; mi < 4; ++mi)
#pragma unroll
    for (int ni = 0; ni < 4; ++ni) {
      const int n = n0 + wn * 64 + ni * 16 + lr;
      const int sidx = n >> 5, c = n & 31;
#pragma unroll
      for (int r = 0; r < 4; ++r) {
        const int i = i0 + wm * 64 + mi * 16 + lq * 4 + r;
        const size_t idx = (((size_t)sidx * N + i) << 8) + h * C + c;
        const float gv = __bfloat162float(gb[idx]);
        gb[idx] = __float2bfloat16(gv * acc[mi][ni][r]);
      }
    }
}

// ---------------------------------------------------------------------------
// Kernel 6 (MFMA, 256x128 tile, 512 thr, XCD-chunked): out = og @ Wp, fp32.
// (r10-exact.)
// ---------------------------------------------------------------------------
__global__ __launch_bounds__(512) void k_out_mfma(
    const __hip_bfloat16* __restrict__ ogb, const __hip_bfloat16* __restrict__ Wp_t,
    float* __restrict__ out)
{
  __shared__ __hip_bfloat16 Ac[8 * 256 * 8];  // 32 KB
  __shared__ __hip_bfloat16 Bc[8 * 128 * 8];  // 16 KB
  const int t = threadIdx.x;
  const int wave = t >> 6, lane = t & 63;
  const int wm = wave >> 1, wn = wave & 1;
  const int lr = lane & 15, lq = lane >> 4;
  const int bid = blockIdx.x;
  const int virt = (bid & 7) * 128 + (bid >> 3);
  const int n0 = (virt & 1) * 128;
  const int m0 = (virt >> 1) * 256;

  f32x4 acc[4][4];
#pragma unroll
  for (int mi = 0; mi < 4; ++mi)
#pragma unroll
    for (int ni = 0; ni < 4; ++ni) acc[mi][ni] = (f32x4)0.f;

  for (int kt = 0; kt < CM / 64; ++kt) {
    __syncthreads();
#pragma unroll
    for (int u = 0; u < 4; ++u) {
      const int cc = wave * 4 + u;
      const int kb = cc & 7, ih = cc >> 3;
      GLOBAL_LOAD_LDS16(ogb + ((size_t)(m0 + ih * 64 + lane)) * CM + kt * 64 + kb * 8,
                        &Ac[(kb * 256 + ih * 64 + lane) * 8]);
    }
#pragma unroll
    for (int u = 0; u < 2; ++u) {
      const int cc = wave * 2 + u;
      const int kb = cc & 7, ih = cc >> 3;
      GLOBAL_LOAD_LDS16(Wp_t + ((size_t)(n0 + ih * 64 + lane)) * CM + kt * 64 + kb * 8,
                        &Bc[(kb * 128 + ih * 64 + lane) * 8]);
    }
    __syncthreads();
#pragma unroll
    for (int kh = 0; kh < 2; ++kh) {
      const int ldb = lq + kh * 4;
      short8v a[4], b[4];
#pragma unroll
      for (int mi = 0; mi < 4; ++mi)
        a[mi] = *(const short8v*)&Ac[((ldb * 256) + wm * 64 + mi * 16 + lr) * 8];
#pragma unroll
      for (int ni = 0; ni < 4; ++ni)
        b[ni] = *(const short8v*)&Bc[((ldb * 128) + wn * 64 + ni * 16 + lr) * 8];
#pragma unroll
      for (int mi = 0; mi < 4; ++mi)
#pragma unroll
        for (int ni = 0; ni < 4; ++ni)
          acc[mi][ni] = __builtin_amdgcn_mfma_f32_16x16x32_bf16(a[mi], b[ni], acc[mi][ni], 0, 0, 0);
    }
  }

#pragma unroll
  for (int mi = 0; mi < 4; ++mi) {
    const int rowb = m0 + wm * 64 + mi * 16 + lq * 4;
#pragma unroll
    for (int ni = 0; ni < 4; ++ni) {
      const int col = n0 + wn * 64 + ni * 16 + lr;
#pragma unroll
      for (int r = 0; r < 4; ++r)
        out[(size_t)(rowb + r) * CM + col] = acc[mi][ni][r];
    }
  }
}

// ---------------------------------------------------------------------------
extern "C" void kernel_launch(void* const* d_in, const int* in_sizes, int n_in,
                              void* d_out, int out_size, void* d_ws, size_t ws_size,
                              hipStream_t stream)
{
  const float* msa      = (const float*)d_in[0];
  const float* pair     = (const float*)d_in[1];
  const float* ln_msa_g = (const float*)d_in[2];
  const float* ln_msa_b = (const float*)d_in[3];
  const float* Wv       = (const float*)d_in[4];
  const float* bv       = (const float*)d_in[5];
  const float* ln_z_g   = (const float*)d_in[6];
  const float* ln_z_b   = (const float*)d_in[7];
  const float* Wb       = (const float*)d_in[8];
  const float* bb       = (const float*)d_in[9];
  const float* Wg       = (const float*)d_in[10];
  const float* bg       = (const float*)d_in[11];
  const float* Wp       = (const float*)d_in[12];
  float* out = (float*)d_out;
  (void)bb;  // softmax is shift-invariant; bb cancels

  // ws layout (bytes)
  char* w = (char*)d_ws;
  __hip_bfloat16* vc     = (__hip_bfloat16*)(w);                     // 67.1 MB [h][j/8][s*32+c][j%8]
  __hip_bfloat16* mbf    = (__hip_bfloat16*)(w + 67108864);          // 67.1 MB [row][k]
  __hip_bfloat16* gb     = (__hip_bfloat16*)(w + 134217728);         // 67.1 MB [row][h*32+c] (g, then og)
  __hip_bfloat16* wbh    = (__hip_bfloat16*)(w + 209715200);         //  4.2 MB [h][i][j] bf16
  __hip_bfloat16* Wcat_t = (__hip_bfloat16*)(w + 213909504);         //  256 KB [n][k]
  __hip_bfloat16* Wp_t   = (__hip_bfloat16*)(w + 214171648);         //  128 KB [n][k]

  k_prep<<<256, 256, 0, stream>>>(Wv, Wg, Wp, Wcat_t, Wp_t);
  k_ln<<<S * N / 4, 256, 0, stream>>>(msa, ln_msa_g, ln_msa_b, mbf);
  k_mm1<<<2048, 512, 0, stream>>>(mbf, Wcat_t, bv, bg, vc, gb);
  k_lnb_sm<<<N, 256, 0, stream>>>(pair, ln_z_g, ln_z_b, Wb, wbh);
  k_attn_mfma<<<1024, 512, 0, stream>>>(vc, wbh, gb);
  k_out_mfma<<<1024, 512, 0, stream>>>(gb, Wp_t, out);
}

// Round 15
// 327.077 us; speedup vs baseline: 1.1169x; 1.0438x over previous
//
#include <hip/hip_runtime.h>
#include <hip/hip_bf16.h>
#include <math.h>

#define S 256
#define N 512
#define CM 256
#define CZ 128
#define H 8
#define C 32
#define HC 256

typedef __attribute__((ext_vector_type(8))) short short8v;
typedef __attribute__((ext_vector_type(4))) float f32x4;

#define GLOBAL_LOAD_LDS16(gsrc, ldst)                                          \
  __builtin_amdgcn_global_load_lds(                                            \
      (const __attribute__((address_space(1))) void*)(gsrc),                   \
      (__attribute__((address_space(3))) void*)(ldst), 16, 0, 0)

// ---------------------------------------------------------------------------
// Kernel 0: weight prep. Wcat_t[n][k] = bf16(Wv[k][n]) (n<256) / Wg[k][n-256];
// Wp_t[n][k] = bf16(Wp[k][n]).  B^T layouts for MFMA B-fragments.
// ---------------------------------------------------------------------------
__global__ __launch_bounds__(256) void k_prep(
    const float* __restrict__ Wv, const float* __restrict__ Wg, const float* __restrict__ Wp,
    __hip_bfloat16* __restrict__ Wcat_t, __hip_bfloat16* __restrict__ Wp_t)
{
  const int k = blockIdx.x;   // 256
  const int n = threadIdx.x;  // 256
  Wcat_t[(size_t)n * CM + k]        = __float2bfloat16(Wv[(size_t)k * HC + n]);
  Wcat_t[(size_t)(n + HC) * CM + k] = __float2bfloat16(Wg[(size_t)k * HC + n]);
  Wp_t[(size_t)n * CM + k]          = __float2bfloat16(Wp[(size_t)k * CM + n]);
}

// ---------------------------------------------------------------------------
// Kernel 1: row LayerNorm of msa -> bf16 [131072][256]. One wave per row.
// ---------------------------------------------------------------------------
__global__ __launch_bounds__(256) void k_ln(
    const float* __restrict__ msa, const float* __restrict__ gamma, const float* __restrict__ beta,
    __hip_bfloat16* __restrict__ mbf)
{
  const int t = threadIdx.x, wav = t >> 6, lane = t & 63;
  const size_t row = (size_t)blockIdx.x * 4 + wav;
  const int k0 = lane * 4;
  const float4 xv = *(const float4*)(msa + row * CM + k0);
  float s  = xv.x + xv.y + xv.z + xv.w;
  float s2 = xv.x * xv.x + xv.y * xv.y + xv.z * xv.z + xv.w * xv.w;
#pragma unroll
  for (int off = 32; off > 0; off >>= 1) {
    s  += __shfl_xor(s, off);
    s2 += __shfl_xor(s2, off);
  }
  const float mu = s * (1.f / CM);
  const float rstd = rsqrtf(s2 * (1.f / CM) - mu * mu + 1e-5f);
  const float4 gm = *(const float4*)(gamma + k0);
  const float4 bt = *(const float4*)(beta + k0);
  union { __hip_bfloat16 b[4]; short4 v; } pk;
  pk.b[0] = __float2bfloat16((xv.x - mu) * rstd * gm.x + bt.x);
  pk.b[1] = __float2bfloat16((xv.y - mu) * rstd * gm.y + bt.y);
  pk.b[2] = __float2bfloat16((xv.z - mu) * rstd * gm.z + bt.z);
  pk.b[3] = __float2bfloat16((xv.w - mu) * rstd * gm.w + bt.w);
  *(short4*)(mbf + row * CM + k0) = pk.v;
}

// ---------------------------------------------------------------------------
// Kernel 2 (MFMA, 256x128 tile, 512 thr, single-buffer, XCD-chunked):
// D = mbf @ Wcat + bias.  (r10-exact, best measured.)
// ---------------------------------------------------------------------------
__global__ __launch_bounds__(512) void k_mm1(
    const __hip_bfloat16* __restrict__ mbf, const __hip_bfloat16* __restrict__ Wcat_t,
    const float* __restrict__ bv, const float* __restrict__ bg,
    __hip_bfloat16* __restrict__ vc, __hip_bfloat16* __restrict__ gb)
{
  __shared__ __hip_bfloat16 Ac[8 * 256 * 8];  // 32 KB [kb][mrow][kr]
  __shared__ __hip_bfloat16 Bc[8 * 128 * 8];  // 16 KB [kb][nrow][kr]
  const int t = threadIdx.x;
  const int wave = t >> 6, lane = t & 63;
  const int wm = wave >> 1, wn = wave & 1;     // 4m x 2n
  const int lr = lane & 15, lq = lane >> 4;
  const int bid = blockIdx.x;
  const int virt = (bid & 7) * 256 + (bid >> 3);
  const int n0 = (virt & 3) * 128;
  const int m0 = (virt >> 2) * 256;
  const bool vhalf = (n0 < HC);

  float bias[4];
#pragma unroll
  for (int ni = 0; ni < 4; ++ni) {
    const int col = n0 + wn * 64 + ni * 16 + lr;
    bias[ni] = vhalf ? bv[col] : bg[col - HC];
  }
  f32x4 acc[4][4];
#pragma unroll
  for (int mi = 0; mi < 4; ++mi)
#pragma unroll
    for (int ni = 0; ni < 4; ++ni) acc[mi][ni] = (f32x4)bias[ni];

  for (int kt = 0; kt < CM / 64; ++kt) {
    __syncthreads();
#pragma unroll
    for (int u = 0; u < 4; ++u) {       // A: 32 chunks of 1KB
      const int cc = wave * 4 + u;
      const int kb = cc & 7, ih = cc >> 3;
      GLOBAL_LOAD_LDS16(mbf + ((size_t)(m0 + ih * 64 + lane)) * CM + kt * 64 + kb * 8,
                        &Ac[(kb * 256 + ih * 64 + lane) * 8]);
    }
#pragma unroll
    for (int u = 0; u < 2; ++u) {       // B: 16 chunks
      const int cc = wave * 2 + u;
      const int kb = cc & 7, ih = cc >> 3;
      GLOBAL_LOAD_LDS16(Wcat_t + ((size_t)(n0 + ih * 64 + lane)) * CM + kt * 64 + kb * 8,
                        &Bc[(kb * 128 + ih * 64 + lane) * 8]);
    }
    __syncthreads();
#pragma unroll
    for (int kh = 0; kh < 2; ++kh) {
      const int ldb = lq + kh * 4;
      short8v a[4], b[4];
#pragma unroll
      for (int mi = 0; mi < 4; ++mi)
        a[mi] = *(const short8v*)&Ac[((ldb * 256) + wm * 64 + mi * 16 + lr) * 8];
#pragma unroll
      for (int ni = 0; ni < 4; ++ni)
        b[ni] = *(const short8v*)&Bc[((ldb * 128) + wn * 64 + ni * 16 + lr) * 8];
#pragma unroll
      for (int mi = 0; mi < 4; ++mi)
#pragma unroll
        for (int ni = 0; ni < 4; ++ni)
          acc[mi][ni] = __builtin_amdgcn_mfma_f32_16x16x32_bf16(a[mi], b[ni], acc[mi][ni], 0, 0, 0);
    }
  }

  if (vhalf) {  // v -> chunked layout, 4 consecutive j per lane = 8B store
#pragma unroll
    for (int mi = 0; mi < 4; ++mi) {
      const int rowb = m0 + wm * 64 + mi * 16 + lq * 4;
      const int s = rowb >> 9;
      const int j = rowb & (N - 1);
      const int jb = j >> 3, jlo = (lq & 1) * 4;
#pragma unroll
      for (int ni = 0; ni < 4; ++ni) {
        const int col = n0 + wn * 64 + ni * 16 + lr;
        const int h = col >> 5, c = col & 31;
        union { __hip_bfloat16 b[4]; short4 v; } pk;
#pragma unroll
        for (int r = 0; r < 4; ++r) pk.b[r] = __float2bfloat16(acc[mi][ni][r]);
        *(short4*)(vc + ((size_t)(h * (N / 8) + jb) * (S * C) + s * C + c) * 8 + jlo) = pk.v;
      }
    }
  } else {  // g half
#pragma unroll
    for (int mi = 0; mi < 4; ++mi) {
      const int rowb = m0 + wm * 64 + mi * 16 + lq * 4;
#pragma unroll
      for (int ni = 0; ni < 4; ++ni) {
        const int colp = (n0 - HC) + wn * 64 + ni * 16 + lr;
#pragma unroll
        for (int r = 0; r < 4; ++r)
          gb[(size_t)(rowb + r) * HC + colp] =
              __float2bfloat16(1.f / (1.f + __expf(-acc[mi][ni][r])));
      }
    }
  }
}

// ---------------------------------------------------------------------------
// Kernel 3 (fused): LayerNorm(pair) @ Wb -> softmax over j -> wbh [h][i][j].
// ---------------------------------------------------------------------------
__global__ __launch_bounds__(256) void k_lnb_sm(
    const float* __restrict__ pair, const float* __restrict__ gamma, const float* __restrict__ beta,
    const float* __restrict__ Wb, __hip_bfloat16* __restrict__ wbh)
{
  __shared__ float slog[H][N];  // 16 KB
  const int t = threadIdx.x, wav = t >> 6, lane = t & 63;
  const int q = lane & 15, sub = lane >> 4;  // 4 rows per wave per iter
  const int k0 = q * 8;
  const size_t i = blockIdx.x;

  float wreg[8][8];
#pragma unroll
  for (int kk = 0; kk < 8; ++kk) {
    *(float4*)&wreg[kk][0] = *(const float4*)&Wb[(k0 + kk) * H];
    *(float4*)&wreg[kk][4] = *(const float4*)&Wb[(k0 + kk) * H + 4];
  }
  const float4 gm0 = *(const float4*)(gamma + k0);
  const float4 gm1 = *(const float4*)(gamma + k0 + 4);
  const float4 bt0 = *(const float4*)(beta + k0);
  const float4 bt1 = *(const float4*)(beta + k0 + 4);

#pragma unroll 2
  for (int it = 0; it < 32; ++it) {
    const int j = it * 16 + wav * 4 + sub;
    const float* x = pair + (i * N + j) * CZ + k0;
    const float4 x0 = *(const float4*)(x);
    const float4 x1 = *(const float4*)(x + 4);

    float s  = x0.x + x0.y + x0.z + x0.w + x1.x + x1.y + x1.z + x1.w;
    float s2 = x0.x * x0.x + x0.y * x0.y + x0.z * x0.z + x0.w * x0.w
             + x1.x * x1.x + x1.y * x1.y + x1.z * x1.z + x1.w * x1.w;
#pragma unroll
    for (int off = 8; off > 0; off >>= 1) {
      s  += __shfl_xor(s, off);
      s2 += __shfl_xor(s2, off);
    }
    const float mu = s * (1.f / CZ);
    const float rstd = rsqrtf(s2 * (1.f / CZ) - mu * mu + 1e-5f);

    float xn[8];
    xn[0] = (x0.x - mu) * rstd * gm0.x + bt0.x;
    xn[1] = (x0.y - mu) * rstd * gm0.y + bt0.y;
    xn[2] = (x0.z - mu) * rstd * gm0.z + bt0.z;
    xn[3] = (x0.w - mu) * rstd * gm0.w + bt0.w;
    xn[4] = (x1.x - mu) * rstd * gm1.x + bt1.x;
    xn[5] = (x1.y - mu) * rstd * gm1.y + bt1.y;
    xn[6] = (x1.z - mu) * rstd * gm1.z + bt1.z;
    xn[7] = (x1.w - mu) * rstd * gm1.w + bt1.w;

    float acc[8];
#pragma unroll
    for (int h = 0; h < 8; ++h) acc[h] = 0.f;
#pragma unroll
    for (int kk = 0; kk < 8; ++kk)
#pragma unroll
      for (int h = 0; h < 8; ++h) acc[h] += xn[kk] * wreg[kk][h];

#pragma unroll
    for (int h = 0; h < 8; ++h) {
#pragma unroll
      for (int off = 8; off > 0; off >>= 1) acc[h] += __shfl_xor(acc[h], off);
    }
    if (q == 0) {
#pragma unroll
      for (int h = 0; h < 8; ++h) slog[h][j] = acc[h];
    }
  }
  __syncthreads();

#pragma unroll
  for (int hh2 = 0; hh2 < 2; ++hh2) {
    const int hh = wav * 2 + hh2;
    const int j0 = lane * 8;
    const float4 p0 = *(const float4*)&slog[hh][j0];
    const float4 p1 = *(const float4*)&slog[hh][j0 + 4];
    float mx = fmaxf(fmaxf(fmaxf(p0.x, p0.y), fmaxf(p0.z, p0.w)),
                     fmaxf(fmaxf(p1.x, p1.y), fmaxf(p1.z, p1.w)));
#pragma unroll
    for (int off = 32; off > 0; off >>= 1) mx = fmaxf(mx, __shfl_xor(mx, off));
    float e[8];
    e[0] = __expf(p0.x - mx); e[1] = __expf(p0.y - mx);
    e[2] = __expf(p0.z - mx); e[3] = __expf(p0.w - mx);
    e[4] = __expf(p1.x - mx); e[5] = __expf(p1.y - mx);
    e[6] = __expf(p1.z - mx); e[7] = __expf(p1.w - mx);
    float sum = ((e[0] + e[1]) + (e[2] + e[3])) + ((e[4] + e[5]) + (e[6] + e[7]));
#pragma unroll
    for (int off = 32; off > 0; off >>= 1) sum += __shfl_xor(sum, off);
    const float inv = 1.f / sum;
    union { __hip_bfloat16 b[8]; short8v v; } pk;
#pragma unroll
    for (int r = 0; r < 8; ++r) pk.b[r] = __float2bfloat16(e[r] * inv);
    *(short8v*)(wbh + ((size_t)hh * N + i) * N + j0) = pk.v;
  }
}

// ---------------------------------------------------------------------------
// Kernel 5 (MFMA, 256x128 tile, 512 thr, single-buffer, XCD-chunked): per h,
// O[i][(s,c)] = W_h[i][j] x V_h[j][(s,c)], gate RMW epilogue.  (r10-exact.)
// ---------------------------------------------------------------------------
__global__ __launch_bounds__(512) void k_attn_mfma(
    const __hip_bfloat16* __restrict__ vc, const __hip_bfloat16* __restrict__ wbh,
    __hip_bfloat16* gb)
{
  __shared__ __hip_bfloat16 Ac[8 * 256 * 8];  // 32 KB [kb][irow][jr]
  __shared__ __hip_bfloat16 Bc[8 * 128 * 8];  // 16 KB [kb][nrow][jr]

  const int t = threadIdx.x;
  const int wave = t >> 6, lane = t & 63;
  const int wm = wave >> 1, wn = wave & 1;
  const int lr = lane & 15, lq = lane >> 4;
  const int bid = blockIdx.x;
  const int virt = (bid & 7) * 128 + (bid >> 3);
  const int h  = virt >> 7;
  const int w_ = virt & 127;
  const int i0 = (w_ >> 6) * 256;
  const int n0 = (w_ & 63) * 128;

  f32x4 acc[4][4];
#pragma unroll
  for (int mi = 0; mi < 4; ++mi)
#pragma unroll
    for (int ni = 0; ni < 4; ++ni) acc[mi][ni] = (f32x4)0.f;

  const __hip_bfloat16* Abase = wbh + ((size_t)h * N + i0) * N;
  const __hip_bfloat16* Bbase = vc + (size_t)h * (N / 8) * (S * C) * 8 + (size_t)n0 * 8;

  for (int kt = 0; kt < N / 64; ++kt) {
    __syncthreads();
#pragma unroll
    for (int u = 0; u < 4; ++u) {       // A: 32 chunks
      const int cc = wave * 4 + u;
      const int kb = cc & 7, ih = cc >> 3;
      GLOBAL_LOAD_LDS16(Abase + ((size_t)(ih * 64 + lane)) * N + kt * 64 + kb * 8,
                        &Ac[(kb * 256 + ih * 64 + lane) * 8]);
    }
#pragma unroll
    for (int u = 0; u < 2; ++u) {       // B: 16 chunks
      const int cc = wave * 2 + u;
      const int kb = cc & 7, ih = cc >> 3;
      GLOBAL_LOAD_LDS16(Bbase + ((size_t)(kt * 8 + kb) * (S * C) + ih * 64 + lane) * 8,
                        &Bc[(kb * 128 + ih * 64 + lane) * 8]);
    }
    __syncthreads();

#pragma unroll
    for (int kh = 0; kh < 2; ++kh) {
      const int ldb = lq + kh * 4;
      short8v a[4], b[4];
#pragma unroll
      for (int mi = 0; mi < 4; ++mi)
        a[mi] = *(const short8v*)&Ac[((ldb * 256) + wm * 64 + mi * 16 + lr) * 8];
#pragma unroll
      for (int ni = 0; ni < 4; ++ni)
        b[ni] = *(const short8v*)&Bc[((ldb * 128) + wn * 64 + ni * 16 + lr) * 8];
#pragma unroll
      for (int mi = 0; mi < 4; ++mi)
#pragma unroll
        for (int ni = 0; ni < 4; ++ni)
          acc[mi][ni] = __builtin_amdgcn_mfma_f32_16x16x32_bf16(a[mi], b[ni], acc[mi][ni], 0, 0, 0);
    }
  }

  // epilogue: gate RMW
#pragma unroll
  for (int mi = 0; mi < 4; ++mi)
#pragma unroll
    for (int ni = 0; ni < 4; ++ni) {
      const int n = n0 + wn * 64 + ni * 16 + lr;
      const int sidx = n >> 5, c = n & 31;
#pragma unroll
      for (int r = 0; r < 4; ++r) {
        const int i = i0 + wm * 64 + mi * 16 + lq * 4 + r;
        const size_t idx = (((size_t)sidx * N + i) << 8) + h * C + c;
        const float gv = __bfloat162float(gb[idx]);
        gb[idx] = __float2bfloat16(gv * acc[mi][ni][r]);
      }
    }
}

// ---------------------------------------------------------------------------
// Kernel 6 (MFMA, 256x128 tile, 512 thr, XCD-chunked): out = og @ Wp, fp32.
// (r10-exact.)
// ---------------------------------------------------------------------------
__global__ __launch_bounds__(512) void k_out_mfma(
    const __hip_bfloat16* __restrict__ ogb, const __hip_bfloat16* __restrict__ Wp_t,
    float* __restrict__ out)
{
  __shared__ __hip_bfloat16 Ac[8 * 256 * 8];  // 32 KB
  __shared__ __hip_bfloat16 Bc[8 * 128 * 8];  // 16 KB
  const int t = threadIdx.x;
  const int wave = t >> 6, lane = t & 63;
  const int wm = wave >> 1, wn = wave & 1;
  const int lr = lane & 15, lq = lane >> 4;
  const int bid = blockIdx.x;
  const int virt = (bid & 7) * 128 + (bid >> 3);
  const int n0 = (virt & 1) * 128;
  const int m0 = (virt >> 1) * 256;

  f32x4 acc[4][4];
#pragma unroll
  for (int mi = 0; mi < 4; ++mi)
#pragma unroll
    for (int ni = 0; ni < 4; ++ni) acc[mi][ni] = (f32x4)0.f;

  for (int kt = 0; kt < CM / 64; ++kt) {
    __syncthreads();
#pragma unroll
    for (int u = 0; u < 4; ++u) {
      const int cc = wave * 4 + u;
      const int kb = cc & 7, ih = cc >> 3;
      GLOBAL_LOAD_LDS16(ogb + ((size_t)(m0 + ih * 64 + lane)) * CM + kt * 64 + kb * 8,
                        &Ac[(kb * 256 + ih * 64 + lane) * 8]);
    }
#pragma unroll
    for (int u = 0; u < 2; ++u) {
      const int cc = wave * 2 + u;
      const int kb = cc & 7, ih = cc >> 3;
      GLOBAL_LOAD_LDS16(Wp_t + ((size_t)(n0 + ih * 64 + lane)) * CM + kt * 64 + kb * 8,
                        &Bc[(kb * 128 + ih * 64 + lane) * 8]);
    }
    __syncthreads();
#pragma unroll
    for (int kh = 0; kh < 2; ++kh) {
      const int ldb = lq + kh * 4;
      short8v a[4], b[4];
#pragma unroll
      for (int mi = 0; mi < 4; ++mi)
        a[mi] = *(const short8v*)&Ac[((ldb * 256) + wm * 64 + mi * 16 + lr) * 8];
#pragma unroll
      for (int ni = 0; ni < 4; ++ni)
        b[ni] = *(const short8v*)&Bc[((ldb * 128) + wn * 64 + ni * 16 + lr) * 8];
#pragma unroll
      for (int mi = 0; mi < 4; ++mi)
#pragma unroll
        for (int ni = 0; ni < 4; ++ni)
          acc[mi][ni] = __builtin_amdgcn_mfma_f32_16x16x32_bf16(a[mi], b[ni], acc[mi][ni], 0, 0, 0);
    }
  }

#pragma unroll
  for (int mi = 0; mi < 4; ++mi) {
    const int rowb = m0 + wm * 64 + mi * 16 + lq * 4;
#pragma unroll
    for (int ni = 0; ni < 4; ++ni) {
      const int col = n0 + wn * 64 + ni * 16 + lr;
#pragma unroll
      for (int r = 0; r < 4; ++r)
        out[(size_t)(rowb + r) * CM + col] = acc[mi][ni][r];
    }
  }
}

// ---------------------------------------------------------------------------
extern "C" void kernel_launch(void* const* d_in, const int* in_sizes, int n_in,
                              void* d_out, int out_size, void* d_ws, size_t ws_size,
                              hipStream_t stream)
{
  const float* msa      = (const float*)d_in[0];
  const float* pair     = (const float*)d_in[1];
  const float* ln_msa_g = (const float*)d_in[2];
  const float* ln_msa_b = (const float*)d_in[3];
  const float* Wv       = (const float*)d_in[4];
  const float* bv       = (const float*)d_in[5];
  const float* ln_z_g   = (const float*)d_in[6];
  const float* ln_z_b   = (const float*)d_in[7];
  const float* Wb       = (const float*)d_in[8];
  const float* bb       = (const float*)d_in[9];
  const float* Wg       = (const float*)d_in[10];
  const float* bg       = (const float*)d_in[11];
  const float* Wp       = (const float*)d_in[12];
  float* out = (float*)d_out;
  (void)bb;  // softmax is shift-invariant; bb cancels

  // ws layout (bytes)
  char* w = (char*)d_ws;
  __hip_bfloat16* vc     = (__hip_bfloat16*)(w);                     // 67.1 MB [h][j/8][s*32+c][j%8]
  __hip_bfloat16* mbf    = (__hip_bfloat16*)(w + 67108864);          // 67.1 MB [row][k]
  __hip_bfloat16* gb     = (__hip_bfloat16*)(w + 134217728);         // 67.1 MB [row][h*32+c] (g, then og)
  __hip_bfloat16* wbh    = (__hip_bfloat16*)(w + 209715200);         //  4.2 MB [h][i][j] bf16
  __hip_bfloat16* Wcat_t = (__hip_bfloat16*)(w + 213909504);         //  256 KB [n][k]
  __hip_bfloat16* Wp_t   = (__hip_bfloat16*)(w + 214171648);         //  128 KB [n][k]

  k_prep<<<256, 256, 0, stream>>>(Wv, Wg, Wp, Wcat_t, Wp_t);
  k_ln<<<S * N / 4, 256, 0, stream>>>(msa, ln_msa_g, ln_msa_b, mbf);
  k_mm1<<<2048, 512, 0, stream>>>(mbf, Wcat_t, bv, bg, vc, gb);
  k_lnb_sm<<<N, 256, 0, stream>>>(pair, ln_z_g, ln_z_b, Wb, wbh);
  k_attn_mfma<<<1024, 512, 0, stream>>>(vc, wbh, gb);
  k_out_mfma<<<1024, 512, 0, stream>>>(gb, Wp_t, out);
}